// Round 18
// baseline (366.270 us; speedup 1.0000x reference)
//
#include <hip/hip_runtime.h>
#include <math.h>

#define EPS 1e-4f

__device__ __forceinline__ float sigmoidf_(float x){ return 1.0f/(1.0f+expf(-x)); }

// ---- ordered-uint mapping for float atomic min/max ----
__device__ __forceinline__ unsigned f2u_(float f){
    unsigned u = __float_as_uint(f);
    return (u & 0x80000000u) ? ~u : (u | 0x80000000u);
}
__device__ __forceinline__ float u2f_(unsigned u){
    unsigned b = (u & 0x80000000u) ? (u & 0x7FFFFFFFu) : ~u;
    return __uint_as_float(b);
}

// ================= min/max of pos =================
__global__ void minmax_kernel(const float* __restrict__ p, int n, unsigned* mm){
    float lo = INFINITY, hi = -INFINITY;
    for (int i = blockIdx.x*blockDim.x + threadIdx.x; i < n; i += gridDim.x*blockDim.x){
        float v = p[i]; lo = fminf(lo, v); hi = fmaxf(hi, v);
    }
    for (int off = 32; off > 0; off >>= 1){
        lo = fminf(lo, __shfl_down(lo, off));
        hi = fmaxf(hi, __shfl_down(hi, off));
    }
    __shared__ float slo[8], shi[8];
    int wid = threadIdx.x >> 6;
    if ((threadIdx.x & 63) == 0){ slo[wid] = lo; shi[wid] = hi; }
    __syncthreads();
    if (threadIdx.x == 0){
        int nw = blockDim.x >> 6;
        for (int w = 1; w < nw; w++){ lo = fminf(lo, slo[w]); hi = fmaxf(hi, shi[w]); }
        atomicMin(&mm[0], f2u_(lo));
        atomicMax(&mm[1], f2u_(hi));
    }
}

// ================= 4-way split linked-list grouping =================
// R17: single chain/node -> serial 16-hop nxt pointer chase, 3 waves/CU,
// 1.3TB/s effective. Edge e goes to sub-chain (e&3): the walker holds 4
// independent cursors -> 4x memory-level parallelism, ~4-hop chains.
__global__ void elist_edge(const int* __restrict__ ei, int* __restrict__ head,
                           int* __restrict__ nxt, int E, int N){
    int e = blockIdx.x*blockDim.x + threadIdx.x;
    if (e >= E) return;
    int d = ei[E + e];
    nxt[e] = atomicExch(&head[(e & 3)*N + d], e);
}

__device__ __forceinline__ int voxel_id(const float* __restrict__ pos, int n, int G,
                                        float start, float size){
    int g[3];
    #pragma unroll
    for (int k = 0; k < 3; k++){
        float gg = floorf((pos[(size_t)n*3 + k] - start) / size);
        gg = fminf(fmaxf(gg, 0.f), (float)(G - 1));
        g[k] = (int)gg;
    }
    return (g[0]*G + g[1])*G + g[2];
}

__device__ __forceinline__ void pool_geom(const unsigned* mm, int G, int mode,
                                          float& start, float& size){
    float mn = u2f_(mm[0]), mx = u2f_(mm[1]);
    if (mode == 0){ start = mn; size = (mx + 0.001f - mn) / (float)G; }
    else          { start = mn - 0.5f; size = mx - mn + 1.0f; }
}

__global__ void elist_node(const float* __restrict__ pos, int* __restrict__ head,
                           int* __restrict__ nxt, int N, int G, int mode,
                           const unsigned* __restrict__ mm){
    int n = blockIdx.x*blockDim.x + threadIdx.x;
    if (n >= N) return;
    float start, size; pool_geom(mm, G, mode, start, size);
    int v = voxel_id(pos, n, G, start, size);
    nxt[n] = atomicExch(&head[v], n);
}

// ================= fused spline gather + node finalize (4-chain walk) =========
__global__ __launch_bounds__(64)
void spline_node_kernel(const float* __restrict__ x, const float* __restrict__ pseudo,
                        const int* __restrict__ ei,
                        const int* __restrict__ head, const int* __restrict__ nxt,
                        const float* __restrict__ W,
                        const float* __restrict__ root, const float* __restrict__ bias,
                        const float* __restrict__ lin_w, const float* __restrict__ lin_b,
                        float* __restrict__ pose, float* __restrict__ act, int N, int E){
    __shared__ float Ws[125*17];
    for (int i = threadIdx.x; i < 125*16; i += blockDim.x)
        Ws[(i >> 4)*17 + (i & 15)] = W[i];
    __syncthreads();
    int n = blockIdx.x*blockDim.x + threadIdx.x;
    if (n >= N) return;

    float agg[16];
    #pragma unroll
    for (int o = 0; o < 16; o++) agg[o] = 0.f;

    int e0 = head[0*N + n];
    int e1 = head[1*N + n];
    int e2 = head[2*N + n];
    int e3 = head[3*N + n];
    int cnt = 0;

    auto body = [&](int e){
        float p0 = pseudo[3*e], p1 = pseudo[3*e+1], p2 = pseudo[3*e+2];
        float xv = x[ei[e]];
        float v0 = p0*4.f, v1 = p1*4.f, v2 = p2*4.f;
        float f0 = fminf(fmaxf(floorf(v0), 0.f), 3.f);
        float f1 = fminf(fmaxf(floorf(v1), 0.f), 3.f);
        float f2 = fminf(fmaxf(floorf(v2), 0.f), 3.f);
        float fr0 = v0 - f0, fr1 = v1 - f1, fr2 = v2 - f2;
        int i0 = (int)f0, i1 = (int)f1, i2 = (int)f2;
        #pragma unroll
        for (int b = 0; b < 8; b++){
            int b0 = (b >> 2) & 1, b1 = (b >> 1) & 1, b2 = b & 1;
            float w = (b0 ? fr0 : 1.f - fr0) * (b1 ? fr1 : 1.f - fr1) * (b2 ? fr2 : 1.f - fr2);
            w *= xv;
            int k = ((i0 + b0)*5 + (i1 + b1))*5 + (i2 + b2);
            const float* Wr = &Ws[k*17];
            #pragma unroll
            for (int o = 0; o < 16; o++) agg[o] += w * Wr[o];
        }
        cnt++;
    };

    while ((e0 | e1 | e2 | e3) != -1 || e0 >= 0 || e1 >= 0 || e2 >= 0 || e3 >= 0){
        // prefetch all four next pointers up-front (independent loads)
        int n0 = (e0 >= 0) ? nxt[e0] : -1;
        int n1 = (e1 >= 0) ? nxt[e1] : -1;
        int n2 = (e2 >= 0) ? nxt[e2] : -1;
        int n3 = (e3 >= 0) ? nxt[e3] : -1;
        if (e0 >= 0) body(e0);
        if (e1 >= 0) body(e1);
        if (e2 >= 0) body(e2);
        if (e3 >= 0) body(e3);
        e0 = n0; e1 = n1; e2 = n2; e3 = n3;
        if (e0 < 0 && e1 < 0 && e2 < 0 && e3 < 0) break;
    }

    float deg = fmaxf((float)cnt, 1.0f);
    float xs = x[n];
    float qv0 = lin_b[0], qv1 = lin_b[1], qv2 = lin_b[2], qv3 = lin_b[3];
    #pragma unroll
    for (int o = 0; o < 16; o++){
        float h = agg[o] / deg + xs * root[o] + bias[o];
        float e = (h > 0.f) ? h : expm1f(h);
        qv0 += e * lin_w[o*4 + 0];
        qv1 += e * lin_w[o*4 + 1];
        qv2 += e * lin_w[o*4 + 2];
        qv3 += e * lin_w[o*4 + 3];
    }
    float inv = 1.0f / (sqrtf(qv0*qv0 + qv1*qv1 + qv2*qv2 + qv3*qv3) + EPS);
    pose[(size_t)n*4 + 0] = qv0*inv;
    pose[(size_t)n*4 + 1] = qv1*inv;
    pose[(size_t)n*4 + 2] = qv2*inv;
    pose[(size_t)n*4 + 3] = qv3*inv;
    act[n] = xs;
}

// ====== capsule routing — cooperative, NPB nodes per block ======
template<int I, int J, int NPB>
__global__ __launch_bounds__(NPB*I*J)
void caps_coop_kernel(const float* __restrict__ poseIn, const float* __restrict__ actIn,
                      const float* __restrict__ q, float* __restrict__ poseOut,
                      float* __restrict__ actOut, int N){
    const int IJ = I*J;
    const int tid = threadIdx.x;
    const int nl  = tid / IJ;
    const int li  = tid - nl*IJ;
    const int i   = li / J;
    const int j   = li - i*J;
    const int node = blockIdx.x*NPB + nl;
    const bool on = (node < N);

    __shared__ float redA[NPB][I*J];
    __shared__ float redB[NPB][I*J];
    __shared__ float cp[NPB][I*J*4];
    __shared__ float vsh[NPB][J*4];

    float prx=0.f, pry=0.f, prz=0.f, prw=0.f, ai=0.f;
    if (on){
        float qx = q[li*4+0], qy = q[li*4+1], qz = q[li*4+2], qw = q[li*4+3];
        float qinv = 1.0f/(sqrtf(qx*qx+qy*qy+qz*qz+qw*qw)+EPS);
        qx*=qinv; qy*=qinv; qz*=qinv; qw*=qinv;
        const float* pp = &poseIn[((size_t)node*I + i)*4];
        float rx=pp[0], ry=pp[1], rz=pp[2], rw=pp[3];
        ai = actIn[(size_t)node*I + i];
        float tx = qw*rx + qx*rw + qy*rz - qz*ry;
        float ty = qw*ry - qx*rz + qy*rw + qz*rx;
        float tz = qw*rz + qx*ry - qy*rx + qz*rw;
        float tw = qw*rw - qx*rx - qy*ry - qz*rz;
        float pinv = 1.0f/(sqrtf(tx*tx+ty*ty+tz*tz+tw*tw)+EPS);
        prx=tx*pinv; pry=ty*pinv; prz=tz*pinv; prw=tw*pinv;
    }

    float b = 0.f, c = 0.f;
    for (int t = 0; t < 3; t++){
        redA[nl][li] = b;
        __syncthreads();
        float mb = -INFINITY;
        #pragma unroll
        for (int jj = 0; jj < J; jj++) mb = fmaxf(mb, redA[nl][i*J+jj]);
        float e = expf(b - mb);
        redB[nl][li] = e;
        __syncthreads();
        float s = 0.f;
        #pragma unroll
        for (int jj = 0; jj < J; jj++) s += redB[nl][i*J+jj];
        c = ai * e / s;
        cp[nl][li*4+0] = c*prx; cp[nl][li*4+1] = c*pry;
        cp[nl][li*4+2] = c*prz; cp[nl][li*4+3] = c*prw;
        __syncthreads();
        for (int idx = li; idx < J*4; idx += IJ){
            int jj = idx >> 2, comp = idx & 3;
            float acc = 0.f;
            #pragma unroll
            for (int ii = 0; ii < I; ii++) acc += cp[nl][(ii*J+jj)*4+comp];
            vsh[nl][idx] = acc;
        }
        __syncthreads();
        if (li < J){
            float a0=vsh[nl][li*4], a1=vsh[nl][li*4+1], a2=vsh[nl][li*4+2], a3=vsh[nl][li*4+3];
            float inv = 1.0f/(sqrtf(a0*a0+a1*a1+a2*a2+a3*a3)+EPS);
            vsh[nl][li*4]=a0*inv; vsh[nl][li*4+1]=a1*inv;
            vsh[nl][li*4+2]=a2*inv; vsh[nl][li*4+3]=a3*inv;
        }
        __syncthreads();
        if (t < 2){
            b += prx*vsh[nl][j*4] + pry*vsh[nl][j*4+1] + prz*vsh[nl][j*4+2] + prw*vsh[nl][j*4+3];
            __syncthreads();
        } else {
            redA[nl][li] = c*(prx*vsh[nl][j*4] + pry*vsh[nl][j*4+1]
                            + prz*vsh[nl][j*4+2] + prw*vsh[nl][j*4+3]);
            __syncthreads();
            if (li < J && on){
                float acc = 0.f;
                #pragma unroll
                for (int ii = 0; ii < I; ii++) acc += redA[nl][ii*J+li];
                actOut[(size_t)node*J + li] = sigmoidf_(acc);
                poseOut[((size_t)node*J+li)*4+0] = vsh[nl][li*4+0];
                poseOut[((size_t)node*J+li)*4+1] = vsh[nl][li*4+1];
                poseOut[((size_t)node*J+li)*4+2] = vsh[nl][li*4+2];
                poseOut[((size_t)node*J+li)*4+3] = vsh[nl][li*4+3];
            }
        }
    }
}

// ---------- pool1 (V=32768, ~1.5 nodes/voxel): thread-per-voxel linked-list gather ----------
template<int J>
__global__ __launch_bounds__(256)
void pool1_gather_kernel(const float* __restrict__ pose, const float* __restrict__ act,
                         const float* __restrict__ pos,
                         const int* __restrict__ head, const int* __restrict__ nxt,
                         float* __restrict__ poseOut, float* __restrict__ actOut,
                         float* __restrict__ posOut, int V){
    int v = blockIdx.x*blockDim.x + threadIdx.x;
    if (v >= V) return;

    float s[J][4], w[J], ps0=0.f, ps1=0.f, ps2=0.f;
    #pragma unroll
    for (int j = 0; j < J; j++){ s[j][0]=0.f; s[j][1]=0.f; s[j][2]=0.f; s[j][3]=0.f; w[j]=0.f; }

    int cnt = 0;
    for (int n = head[v]; n >= 0; n = nxt[n]){
        const float* pb = &pose[(size_t)n*J*4];
        const float* ab = &act[(size_t)n*J];
        #pragma unroll
        for (int j = 0; j < J; j++){
            float aj = ab[j];
            s[j][0] += aj*pb[j*4+0];
            s[j][1] += aj*pb[j*4+1];
            s[j][2] += aj*pb[j*4+2];
            s[j][3] += aj*pb[j*4+3];
            w[j] += aj;
        }
        ps0 += pos[(size_t)n*3+0];
        ps1 += pos[(size_t)n*3+1];
        ps2 += pos[(size_t)n*3+2];
        cnt++;
    }
    #pragma unroll
    for (int j = 0; j < J; j++){
        float inv = 1.0f/(sqrtf(s[j][0]*s[j][0]+s[j][1]*s[j][1]+
                                s[j][2]*s[j][2]+s[j][3]*s[j][3])+EPS);
        s[j][0]*=inv; s[j][1]*=inv; s[j][2]*=inv; s[j][3]*=inv;
    }
    float ag[J];
    #pragma unroll
    for (int j = 0; j < J; j++) ag[j] = 0.f;
    for (int n = head[v]; n >= 0; n = nxt[n]){
        const float* pb = &pose[(size_t)n*J*4];
        const float* ab = &act[(size_t)n*J];
        #pragma unroll
        for (int j = 0; j < J; j++){
            float agree = pb[j*4+0]*s[j][0] + pb[j*4+1]*s[j][1]
                        + pb[j*4+2]*s[j][2] + pb[j*4+3]*s[j][3];
            ag[j] += ab[j]*agree;
        }
    }
    #pragma unroll
    for (int j = 0; j < J; j++){
        size_t o = (size_t)v*J + j;
        actOut[o] = sigmoidf_(ag[j] / (w[j] + EPS));
        poseOut[o*4+0] = s[j][0];
        poseOut[o*4+1] = s[j][1];
        poseOut[o*4+2] = s[j][2];
        poseOut[o*4+3] = s[j][3];
    }
    float c = (float)cnt + EPS;
    posOut[(size_t)v*3+0] = ps0 / c;
    posOut[(size_t)v*3+1] = ps1 / c;
    posOut[(size_t)v*3+2] = ps2 / c;
}

// ---------- pools 2-3 (small V, heavy skew): node-parallel LDS-privatized ----------
template<int V, int J, int CH, int NCHUNK>
__global__ void pool_priv1(const float4* __restrict__ poseIn, const float* __restrict__ actIn,
                           const float* __restrict__ posIn,
                           float* __restrict__ s, float* __restrict__ wsum,
                           float* __restrict__ cnt, float* __restrict__ psum,
                           int N, int G, int mode, const unsigned* __restrict__ mm){
    __shared__ float s_[V*CH*4];
    __shared__ float wsum_[V*CH];
    __shared__ float cnt_[V];
    __shared__ float psum_[V*3];
    const int chunk = blockIdx.x % NCHUNK;
    const int slice = blockIdx.x / NCHUNK;
    const int nslices = gridDim.x / NCHUNK;
    const int c0 = chunk * CH;

    for (int t = threadIdx.x; t < V*CH*4; t += blockDim.x) s_[t] = 0.f;
    for (int t = threadIdx.x; t < V*CH; t += blockDim.x) wsum_[t] = 0.f;
    if (chunk == 0){
        for (int t = threadIdx.x; t < V; t += blockDim.x) cnt_[t] = 0.f;
        for (int t = threadIdx.x; t < V*3; t += blockDim.x) psum_[t] = 0.f;
    }
    __syncthreads();

    float start, size; pool_geom(mm, G, mode, start, size);
    int per = (N + nslices - 1) / nslices;
    int n0 = slice * per, n1 = min(N, n0 + per);

    for (int n = n0 + (int)threadIdx.x; n < n1; n += blockDim.x){
        int vid = voxel_id(posIn, n, G, start, size);
        #pragma unroll
        for (int jj = 0; jj < CH; jj++){
            int j = c0 + jj;
            float aj = actIn[(size_t)n*J + j];
            float4 p = poseIn[(size_t)n*J + j];
            int b = (vid*CH + jj)*4;
            atomicAdd(&s_[b+0], aj*p.x);
            atomicAdd(&s_[b+1], aj*p.y);
            atomicAdd(&s_[b+2], aj*p.z);
            atomicAdd(&s_[b+3], aj*p.w);
            atomicAdd(&wsum_[vid*CH + jj], aj);
        }
        if (chunk == 0){
            atomicAdd(&cnt_[vid], 1.0f);
            atomicAdd(&psum_[vid*3+0], posIn[(size_t)n*3+0]);
            atomicAdd(&psum_[vid*3+1], posIn[(size_t)n*3+1]);
            atomicAdd(&psum_[vid*3+2], posIn[(size_t)n*3+2]);
        }
    }
    __syncthreads();

    for (int t = threadIdx.x; t < V*CH*4; t += blockDim.x){
        float val = s_[t];
        if (val != 0.f){
            int v = t / (CH*4), r = t % (CH*4);
            atomicAdd(&s[((size_t)v*J + c0)*4 + r], val);
        }
    }
    for (int t = threadIdx.x; t < V*CH; t += blockDim.x){
        float val = wsum_[t];
        if (val != 0.f){
            int v = t / CH, jj = t % CH;
            atomicAdd(&wsum[(size_t)v*J + c0 + jj], val);
        }
    }
    if (chunk == 0){
        for (int t = threadIdx.x; t < V; t += blockDim.x)
            if (cnt_[t] != 0.f) atomicAdd(&cnt[t], cnt_[t]);
        for (int t = threadIdx.x; t < V*3; t += blockDim.x)
            if (psum_[t] != 0.f) atomicAdd(&psum[t], psum_[t]);
    }
}

template<int V, int J>
__global__ void pool_priv2(const float4* __restrict__ poseIn, const float* __restrict__ actIn,
                           const float* __restrict__ posIn, const float4* __restrict__ m,
                           float* __restrict__ agacc,
                           int N, int G, int mode, const unsigned* __restrict__ mm){
    __shared__ float ag_[V*J];
    for (int t = threadIdx.x; t < V*J; t += blockDim.x) ag_[t] = 0.f;
    __syncthreads();
    float start, size; pool_geom(mm, G, mode, start, size);
    int nslices = gridDim.x;
    int per = (N + nslices - 1) / nslices;
    int n0 = blockIdx.x * per, n1 = min(N, n0 + per);
    for (int n = n0 + (int)threadIdx.x; n < n1; n += blockDim.x){
        int vid = voxel_id(posIn, n, G, start, size);
        #pragma unroll
        for (int j = 0; j < J; j++){
            float4 p  = poseIn[(size_t)n*J + j];
            float4 mv = m[(size_t)vid*J + j];
            float agree = p.x*mv.x + p.y*mv.y + p.z*mv.z + p.w*mv.w;
            atomicAdd(&ag_[vid*J + j], actIn[(size_t)n*J + j]*agree);
        }
    }
    __syncthreads();
    for (int t = threadIdx.x; t < V*J; t += blockDim.x)
        if (ag_[t] != 0.f) atomicAdd(&agacc[t], ag_[t]);
}

__global__ void pool_m(const float* __restrict__ s, float* __restrict__ m, int VJ){
    int t = blockIdx.x*blockDim.x + threadIdx.x;
    if (t >= VJ) return;
    float a = s[(size_t)t*4], b = s[(size_t)t*4+1], c = s[(size_t)t*4+2], d = s[(size_t)t*4+3];
    float inv = 1.0f / (sqrtf(a*a + b*b + c*c + d*d) + EPS);
    m[(size_t)t*4]   = a*inv;
    m[(size_t)t*4+1] = b*inv;
    m[(size_t)t*4+2] = c*inv;
    m[(size_t)t*4+3] = d*inv;
}

__global__ void pool_fin(const float* __restrict__ agacc, const float* __restrict__ wsum,
                         const float* __restrict__ cnt, const float* __restrict__ psum,
                         float* __restrict__ actOut, float* __restrict__ posOut, int V, int J){
    int t = blockIdx.x*blockDim.x + threadIdx.x;
    if (t >= V*J) return;
    int v = t / J, j = t % J;
    actOut[t] = sigmoidf_(agacc[t] / (wsum[t] + EPS));
    if (j == 0){
        float c = cnt[v] + EPS;
        posOut[(size_t)v*3 + 0] = psum[(size_t)v*3 + 0] / c;
        posOut[(size_t)v*3 + 1] = psum[(size_t)v*3 + 1] / c;
        posOut[(size_t)v*3 + 2] = psum[(size_t)v*3 + 2] / c;
    }
}

// ---------- pool4 (N=8 -> V=1): single fused LDS kernel (trivial) ----------
template<int V, int J, int CH>
__global__ void pool_fused_kernel(const float* __restrict__ poseIn, const float* __restrict__ actIn,
                                  const float* __restrict__ posIn,
                                  float* __restrict__ poseOut, float* __restrict__ actOut,
                                  float* __restrict__ posOut,
                                  int N, int G, int mode, const unsigned* __restrict__ mm){
    __shared__ float s_[V*CH*4];
    __shared__ float wsum_[V*CH];
    __shared__ float ag_[V*CH];
    __shared__ float cnt_[V];
    __shared__ float psum_[V*3];
    const int c0 = blockIdx.x * CH;

    for (int t = threadIdx.x; t < V*CH*4; t += blockDim.x) s_[t] = 0.f;
    for (int t = threadIdx.x; t < V*CH; t += blockDim.x){ wsum_[t] = 0.f; ag_[t] = 0.f; }
    if (blockIdx.x == 0){
        for (int t = threadIdx.x; t < V; t += blockDim.x) cnt_[t] = 0.f;
        for (int t = threadIdx.x; t < V*3; t += blockDim.x) psum_[t] = 0.f;
    }
    __syncthreads();

    float start, size; pool_geom(mm, G, mode, start, size);

    for (int n = threadIdx.x; n < N; n += blockDim.x){
        int vid = voxel_id(posIn, n, G, start, size);
        #pragma unroll
        for (int jj = 0; jj < CH; jj++){
            int j = c0 + jj;
            float aj = actIn[(size_t)n*J + j];
            const float* pb = &poseIn[((size_t)n*J + j)*4];
            int b = (vid*CH + jj)*4;
            atomicAdd(&s_[b+0], aj*pb[0]);
            atomicAdd(&s_[b+1], aj*pb[1]);
            atomicAdd(&s_[b+2], aj*pb[2]);
            atomicAdd(&s_[b+3], aj*pb[3]);
            atomicAdd(&wsum_[vid*CH + jj], aj);
        }
        if (blockIdx.x == 0){
            atomicAdd(&cnt_[vid], 1.0f);
            atomicAdd(&psum_[vid*3+0], posIn[(size_t)n*3+0]);
            atomicAdd(&psum_[vid*3+1], posIn[(size_t)n*3+1]);
            atomicAdd(&psum_[vid*3+2], posIn[(size_t)n*3+2]);
        }
    }
    __syncthreads();

    for (int t = threadIdx.x; t < V*CH; t += blockDim.x){
        float a = s_[t*4], b = s_[t*4+1], c = s_[t*4+2], d = s_[t*4+3];
        float inv = 1.0f / (sqrtf(a*a + b*b + c*c + d*d) + EPS);
        s_[t*4] = a*inv; s_[t*4+1] = b*inv; s_[t*4+2] = c*inv; s_[t*4+3] = d*inv;
    }
    __syncthreads();

    for (int n = threadIdx.x; n < N; n += blockDim.x){
        int vid = voxel_id(posIn, n, G, start, size);
        #pragma unroll
        for (int jj = 0; jj < CH; jj++){
            int j = c0 + jj;
            const float* pb = &poseIn[((size_t)n*J + j)*4];
            const float* mb = &s_[(vid*CH + jj)*4];
            float agree = pb[0]*mb[0] + pb[1]*mb[1] + pb[2]*mb[2] + pb[3]*mb[3];
            atomicAdd(&ag_[vid*CH + jj], actIn[(size_t)n*J + j]*agree);
        }
    }
    __syncthreads();

    for (int t = threadIdx.x; t < V*CH; t += blockDim.x){
        int v = t / CH, jj = t % CH;
        size_t o = (size_t)v*J + c0 + jj;
        actOut[o] = sigmoidf_(ag_[t] / (wsum_[t] + EPS));
        poseOut[o*4+0] = s_[t*4+0];
        poseOut[o*4+1] = s_[t*4+1];
        poseOut[o*4+2] = s_[t*4+2];
        poseOut[o*4+3] = s_[t*4+3];
    }
    if (blockIdx.x == 0){
        for (int v = threadIdx.x; v < V; v += blockDim.x){
            float c = cnt_[v] + EPS;
            posOut[(size_t)v*3+0] = psum_[(size_t)v*3+0] / c;
            posOut[(size_t)v*3+1] = psum_[(size_t)v*3+1] / c;
            posOut[(size_t)v*3+2] = psum_[(size_t)v*3+2] / c;
        }
    }
}

extern "C" void kernel_launch(void* const* d_in, const int* in_sizes, int n_in,
                              void* d_out, int out_size, void* d_ws, size_t ws_size,
                              hipStream_t stream){
    const float* x      = (const float*)d_in[0];
    const float* pos    = (const float*)d_in[1];
    const float* pseudo = (const float*)d_in[2];
    const float* Wsp    = (const float*)d_in[3];
    const float* root   = (const float*)d_in[4];
    const float* bias   = (const float*)d_in[5];
    const float* lin_w  = (const float*)d_in[6];
    const float* lin_b  = (const float*)d_in[7];
    const float* q0     = (const float*)d_in[8];
    const float* q1     = (const float*)d_in[9];
    const float* q3     = (const float*)d_in[10];
    const float* q5     = (const float*)d_in[11];
    const float* q6     = (const float*)d_in[12];
    const float* q7     = (const float*)d_in[13];
    const int*   ei     = (const int*)d_in[14];
    const int N = in_sizes[0];
    const int E = in_sizes[2] / 3;
    const int V1 = 32768;

    char* ws = (char*)d_ws;
    size_t off = 0;
    auto alloc = [&](size_t bytes)->void*{
        void* p = ws + off;
        off += (bytes + 255) & ~(size_t)255;
        return p;
    };
    unsigned* mm   = (unsigned*)alloc(8);
    int* ehead     = (int*)alloc((size_t)4*N*sizeof(int));
    int* enxt      = (int*)alloc((size_t)E*sizeof(int));
    int* vhead     = (int*)alloc((size_t)V1*sizeof(int));
    int* vnxt      = (int*)alloc((size_t)N*sizeof(int));
    float* P0  = (float*)alloc((size_t)1250000*sizeof(float));
    float* P1  = (float*)alloc((size_t)1250000*sizeof(float));
    float* A0  = (float*)alloc((size_t)310000*sizeof(float));
    float* A1  = (float*)alloc((size_t)310000*sizeof(float));
    float* PB0 = (float*)alloc((size_t)100000*sizeof(float));
    float* PB1 = (float*)alloc((size_t)100000*sizeof(float));
    size_t pool_off0 = off;                     // shared pool scratch region
    float* vs  = (float*)alloc((size_t)512*8*4*sizeof(float));
    float* vw  = (float*)alloc((size_t)512*8*sizeof(float));
    float* va  = (float*)alloc((size_t)512*8*sizeof(float));
    float* vc  = (float*)alloc((size_t)512*sizeof(float));
    float* vp  = (float*)alloc((size_t)512*3*sizeof(float));
    size_t pool_bytes = off - pool_off0;

    hipMemsetAsync(mm,     0xFF, 4, stream);
    hipMemsetAsync(mm + 1, 0x00, 4, stream);
    hipMemsetAsync(ehead, 0xFF, (size_t)4*N*sizeof(int), stream); // -1
    hipMemsetAsync(vhead, 0xFF, (size_t)V1*sizeof(int), stream);  // -1

    minmax_kernel<<<80, 256, 0, stream>>>(pos, N*3, mm);

    // 4-way split linked-list grouping + fused spline gather / node finalize
    elist_edge<<<(E + 255)/256, 256, 0, stream>>>(ei, ehead, enxt, E, N);
    spline_node_kernel<<<(N + 63)/64, 64, 0, stream>>>(x, pseudo, ei, ehead, enxt, Wsp,
                                                       root, bias, lin_w, lin_b, P0, A0, N, E);

    // capsule layers: all cooperative (spill-free)
    caps_coop_kernel<1,6,32><<<(N + 31)/32, 32*6, 0, stream>>>(P0, A0, q0, P1, A1, N);
    caps_coop_kernel<6,6,7><<<(N + 6)/7, 7*36, 0, stream>>>(P1, A1, q1, P0, A0, N);

    // pool1: 50000 -> 32768 voxels (G=32), J=6 — linked-list thread-per-voxel gather
    {
        const int G = 32;
        elist_node<<<(N + 255)/256, 256, 0, stream>>>(pos, vhead, vnxt, N, G, 0, mm);
        pool1_gather_kernel<6><<<(V1 + 255)/256, 256, 0, stream>>>(P0, A0, pos, vhead, vnxt,
                                                                   P1, A1, PB0, V1);
    }
    caps_coop_kernel<6,8,5><<<(32768 + 4)/5, 5*48, 0, stream>>>(P1, A1, q3, P0, A0, 32768);

    // pool2: 32768 -> 512 (G=8), J=8 — node-parallel LDS-privatized, 64 slices
    {
        const int V = 512, J = 8, G = 8, NSL = 64;
        hipMemsetAsync(vs, 0, pool_bytes, stream);
        pool_priv1<V,J,4,2><<<2*NSL, 256, 0, stream>>>((const float4*)P0, A0, PB0,
                                                       vs, vw, vc, vp, 32768, G, 0, mm);
        pool_m<<<(V*J + 255)/256, 256, 0, stream>>>(vs, P1, V*J);
        pool_priv2<V,J><<<NSL, 256, 0, stream>>>((const float4*)P0, A0, PB0,
                                                 (const float4*)P1, va, 32768, G, 0, mm);
        pool_fin<<<(V*J + 255)/256, 256, 0, stream>>>(va, vw, vc, vp, A1, PB1, V, J);
    }
    caps_coop_kernel<8,12,2><<<256, 2*96, 0, stream>>>(P1, A1, q5, P0, A0, 512);

    // pool3: 512 -> 8 (G=2), J=12 — node-parallel privatized, 16 slices
    {
        const int V = 8, J = 12, G = 2, NSL = 16;
        hipMemsetAsync(vs, 0, pool_bytes, stream);
        pool_priv1<V,J,12,1><<<NSL, 256, 0, stream>>>((const float4*)P0, A0, PB1,
                                                      vs, vw, vc, vp, 512, G, 0, mm);
        pool_m<<<1, 256, 0, stream>>>(vs, P1, V*J);
        pool_priv2<V,J><<<NSL, 256, 0, stream>>>((const float4*)P0, A0, PB1,
                                                 (const float4*)P1, va, 512, G, 0, mm);
        pool_fin<<<1, 256, 0, stream>>>(va, vw, vc, vp, A1, PB0, V, J);
    }
    caps_coop_kernel<12,14,1><<<8, 168, 0, stream>>>(P1, A1, q6, P0, A0, 8);

    // pool4: 8 -> 1 (G=1, mode=1), J=14 — fused LDS path, 1 block (trivial N)
    pool_fused_kernel<1,14,14><<<1, 1024, 0, stream>>>(P0, A0, PB0, P1, A1, PB1, 8, 1, 1, mm);
    caps_coop_kernel<14,10,1><<<1, 140, 0, stream>>>(P1, A1, q7, P0, (float*)d_out, 1);
}

// Round 19
// 334.459 us; speedup vs baseline: 1.0951x; 1.0951x over previous
//
#include <hip/hip_runtime.h>
#include <math.h>

#define EPS 1e-4f

__device__ __forceinline__ float sigmoidf_(float x){ return 1.0f/(1.0f+expf(-x)); }

// ---- ordered-uint mapping for float atomic min/max ----
__device__ __forceinline__ unsigned f2u_(float f){
    unsigned u = __float_as_uint(f);
    return (u & 0x80000000u) ? ~u : (u | 0x80000000u);
}
__device__ __forceinline__ float u2f_(unsigned u){
    unsigned b = (u & 0x80000000u) ? (u & 0x7FFFFFFFu) : ~u;
    return __uint_as_float(b);
}

// ================= min/max of pos =================
__global__ void minmax_kernel(const float* __restrict__ p, int n, unsigned* mm){
    float lo = INFINITY, hi = -INFINITY;
    for (int i = blockIdx.x*blockDim.x + threadIdx.x; i < n; i += gridDim.x*blockDim.x){
        float v = p[i]; lo = fminf(lo, v); hi = fmaxf(hi, v);
    }
    for (int off = 32; off > 0; off >>= 1){
        lo = fminf(lo, __shfl_down(lo, off));
        hi = fmaxf(hi, __shfl_down(hi, off));
    }
    __shared__ float slo[8], shi[8];
    int wid = threadIdx.x >> 6;
    if ((threadIdx.x & 63) == 0){ slo[wid] = lo; shi[wid] = hi; }
    __syncthreads();
    if (threadIdx.x == 0){
        int nw = blockDim.x >> 6;
        for (int w = 1; w < nw; w++){ lo = fminf(lo, slo[w]); hi = fmaxf(hi, shi[w]); }
        atomicMin(&mm[0], f2u_(lo));
        atomicMax(&mm[1], f2u_(hi));
    }
}

// ================= 4-way split linked-list grouping =================
__global__ void elist_edge(const int* __restrict__ ei, int* __restrict__ head,
                           int* __restrict__ nxt, int E, int N){
    int e = blockIdx.x*blockDim.x + threadIdx.x;
    if (e >= E) return;
    int d = ei[E + e];
    nxt[e] = atomicExch(&head[(e & 3)*N + d], e);
}

__device__ __forceinline__ int voxel_id(const float* __restrict__ pos, int n, int G,
                                        float start, float size){
    int g[3];
    #pragma unroll
    for (int k = 0; k < 3; k++){
        float gg = floorf((pos[(size_t)n*3 + k] - start) / size);
        gg = fminf(fmaxf(gg, 0.f), (float)(G - 1));
        g[k] = (int)gg;
    }
    return (g[0]*G + g[1])*G + g[2];
}

__device__ __forceinline__ void pool_geom(const unsigned* mm, int G, int mode,
                                          float& start, float& size){
    float mn = u2f_(mm[0]), mx = u2f_(mm[1]);
    if (mode == 0){ start = mn; size = (mx + 0.001f - mn) / (float)G; }
    else          { start = mn - 0.5f; size = mx - mn + 1.0f; }
}

__global__ void elist_node(const float* __restrict__ pos, int* __restrict__ head,
                           int* __restrict__ nxt, int N, int G, int mode,
                           const unsigned* __restrict__ mm){
    int n = blockIdx.x*blockDim.x + threadIdx.x;
    if (n >= N) return;
    float start, size; pool_geom(mm, G, mode, start, size);
    int v = voxel_id(pos, n, G, start, size);
    nxt[n] = atomicExch(&head[v], n);
}

// ===== fused spline gather + node finalize: thread per (node, sub-chain) =====
// R18's 4-cursor single-thread walk bloated codegen (96 VGPR, 4x inlined body)
// with no extra wave parallelism -> 90us. Here the 4 sub-chains of a node go
// to 4 ADJACENT LANES (tid = n*4+k): 200K threads = ~12 waves/CU, each walking
// a ~4-edge chain; agg reduced with two quad shfl_xor steps, lane k=0 finalizes.
__global__ __launch_bounds__(256)
void spline_node_kernel(const float* __restrict__ x, const float* __restrict__ pseudo,
                        const int* __restrict__ ei,
                        const int* __restrict__ head, const int* __restrict__ nxt,
                        const float* __restrict__ W,
                        const float* __restrict__ root, const float* __restrict__ bias,
                        const float* __restrict__ lin_w, const float* __restrict__ lin_b,
                        float* __restrict__ pose, float* __restrict__ act, int N, int E){
    __shared__ float Ws[125*17];
    for (int i = threadIdx.x; i < 125*16; i += blockDim.x)
        Ws[(i >> 4)*17 + (i & 15)] = W[i];
    __syncthreads();
    int t = blockIdx.x*blockDim.x + threadIdx.x;
    int n = t >> 2;
    int k = t & 3;
    if (n >= N) return;     // quad-uniform guard (all 4 lanes share n)

    float agg[16];
    #pragma unroll
    for (int o = 0; o < 16; o++) agg[o] = 0.f;

    int cnt = 0;
    for (int e = head[k*N + n]; e >= 0; e = nxt[e]){
        float p0 = pseudo[3*e], p1 = pseudo[3*e+1], p2 = pseudo[3*e+2];
        float xv = x[ei[e]];
        float v0 = p0*4.f, v1 = p1*4.f, v2 = p2*4.f;
        float f0 = fminf(fmaxf(floorf(v0), 0.f), 3.f);
        float f1 = fminf(fmaxf(floorf(v1), 0.f), 3.f);
        float f2 = fminf(fmaxf(floorf(v2), 0.f), 3.f);
        float fr0 = v0 - f0, fr1 = v1 - f1, fr2 = v2 - f2;
        int i0 = (int)f0, i1 = (int)f1, i2 = (int)f2;
        #pragma unroll
        for (int b = 0; b < 8; b++){
            int b0 = (b >> 2) & 1, b1 = (b >> 1) & 1, b2 = b & 1;
            float w = (b0 ? fr0 : 1.f - fr0) * (b1 ? fr1 : 1.f - fr1) * (b2 ? fr2 : 1.f - fr2);
            w *= xv;
            int kk = ((i0 + b0)*5 + (i1 + b1))*5 + (i2 + b2);
            const float* Wr = &Ws[kk*17];
            #pragma unroll
            for (int o = 0; o < 16; o++) agg[o] += w * Wr[o];
        }
        cnt++;
    }

    // quad reduction (lanes n*4..n*4+3)
    #pragma unroll
    for (int o = 0; o < 16; o++){
        agg[o] += __shfl_xor(agg[o], 1);
        agg[o] += __shfl_xor(agg[o], 2);
    }
    cnt += __shfl_xor(cnt, 1);
    cnt += __shfl_xor(cnt, 2);

    if (k != 0) return;

    float deg = fmaxf((float)cnt, 1.0f);
    float xs = x[n];
    float qv0 = lin_b[0], qv1 = lin_b[1], qv2 = lin_b[2], qv3 = lin_b[3];
    #pragma unroll
    for (int o = 0; o < 16; o++){
        float h = agg[o] / deg + xs * root[o] + bias[o];
        float e = (h > 0.f) ? h : expm1f(h);
        qv0 += e * lin_w[o*4 + 0];
        qv1 += e * lin_w[o*4 + 1];
        qv2 += e * lin_w[o*4 + 2];
        qv3 += e * lin_w[o*4 + 3];
    }
    float inv = 1.0f / (sqrtf(qv0*qv0 + qv1*qv1 + qv2*qv2 + qv3*qv3) + EPS);
    pose[(size_t)n*4 + 0] = qv0*inv;
    pose[(size_t)n*4 + 1] = qv1*inv;
    pose[(size_t)n*4 + 2] = qv2*inv;
    pose[(size_t)n*4 + 3] = qv3*inv;
    act[n] = xs;
}

// ====== capsule routing — cooperative, NPB nodes per block ======
template<int I, int J, int NPB>
__global__ __launch_bounds__(NPB*I*J)
void caps_coop_kernel(const float* __restrict__ poseIn, const float* __restrict__ actIn,
                      const float* __restrict__ q, float* __restrict__ poseOut,
                      float* __restrict__ actOut, int N){
    const int IJ = I*J;
    const int tid = threadIdx.x;
    const int nl  = tid / IJ;
    const int li  = tid - nl*IJ;
    const int i   = li / J;
    const int j   = li - i*J;
    const int node = blockIdx.x*NPB + nl;
    const bool on = (node < N);

    __shared__ float redA[NPB][I*J];
    __shared__ float redB[NPB][I*J];
    __shared__ float cp[NPB][I*J*4];
    __shared__ float vsh[NPB][J*4];

    float prx=0.f, pry=0.f, prz=0.f, prw=0.f, ai=0.f;
    if (on){
        float qx = q[li*4+0], qy = q[li*4+1], qz = q[li*4+2], qw = q[li*4+3];
        float qinv = 1.0f/(sqrtf(qx*qx+qy*qy+qz*qz+qw*qw)+EPS);
        qx*=qinv; qy*=qinv; qz*=qinv; qw*=qinv;
        const float* pp = &poseIn[((size_t)node*I + i)*4];
        float rx=pp[0], ry=pp[1], rz=pp[2], rw=pp[3];
        ai = actIn[(size_t)node*I + i];
        float tx = qw*rx + qx*rw + qy*rz - qz*ry;
        float ty = qw*ry - qx*rz + qy*rw + qz*rx;
        float tz = qw*rz + qx*ry - qy*rx + qz*rw;
        float tw = qw*rw - qx*rx - qy*ry - qz*rz;
        float pinv = 1.0f/(sqrtf(tx*tx+ty*ty+tz*tz+tw*tw)+EPS);
        prx=tx*pinv; pry=ty*pinv; prz=tz*pinv; prw=tw*pinv;
    }

    float b = 0.f, c = 0.f;
    for (int t = 0; t < 3; t++){
        redA[nl][li] = b;
        __syncthreads();
        float mb = -INFINITY;
        #pragma unroll
        for (int jj = 0; jj < J; jj++) mb = fmaxf(mb, redA[nl][i*J+jj]);
        float e = expf(b - mb);
        redB[nl][li] = e;
        __syncthreads();
        float s = 0.f;
        #pragma unroll
        for (int jj = 0; jj < J; jj++) s += redB[nl][i*J+jj];
        c = ai * e / s;
        cp[nl][li*4+0] = c*prx; cp[nl][li*4+1] = c*pry;
        cp[nl][li*4+2] = c*prz; cp[nl][li*4+3] = c*prw;
        __syncthreads();
        for (int idx = li; idx < J*4; idx += IJ){
            int jj = idx >> 2, comp = idx & 3;
            float acc = 0.f;
            #pragma unroll
            for (int ii = 0; ii < I; ii++) acc += cp[nl][(ii*J+jj)*4+comp];
            vsh[nl][idx] = acc;
        }
        __syncthreads();
        if (li < J){
            float a0=vsh[nl][li*4], a1=vsh[nl][li*4+1], a2=vsh[nl][li*4+2], a3=vsh[nl][li*4+3];
            float inv = 1.0f/(sqrtf(a0*a0+a1*a1+a2*a2+a3*a3)+EPS);
            vsh[nl][li*4]=a0*inv; vsh[nl][li*4+1]=a1*inv;
            vsh[nl][li*4+2]=a2*inv; vsh[nl][li*4+3]=a3*inv;
        }
        __syncthreads();
        if (t < 2){
            b += prx*vsh[nl][j*4] + pry*vsh[nl][j*4+1] + prz*vsh[nl][j*4+2] + prw*vsh[nl][j*4+3];
            __syncthreads();
        } else {
            redA[nl][li] = c*(prx*vsh[nl][j*4] + pry*vsh[nl][j*4+1]
                            + prz*vsh[nl][j*4+2] + prw*vsh[nl][j*4+3]);
            __syncthreads();
            if (li < J && on){
                float acc = 0.f;
                #pragma unroll
                for (int ii = 0; ii < I; ii++) acc += redA[nl][ii*J+li];
                actOut[(size_t)node*J + li] = sigmoidf_(acc);
                poseOut[((size_t)node*J+li)*4+0] = vsh[nl][li*4+0];
                poseOut[((size_t)node*J+li)*4+1] = vsh[nl][li*4+1];
                poseOut[((size_t)node*J+li)*4+2] = vsh[nl][li*4+2];
                poseOut[((size_t)node*J+li)*4+3] = vsh[nl][li*4+3];
            }
        }
    }
}

// ---------- pool1 (V=32768, ~1.5 nodes/voxel): thread-per-voxel linked-list gather ----------
template<int J>
__global__ __launch_bounds__(256)
void pool1_gather_kernel(const float* __restrict__ pose, const float* __restrict__ act,
                         const float* __restrict__ pos,
                         const int* __restrict__ head, const int* __restrict__ nxt,
                         float* __restrict__ poseOut, float* __restrict__ actOut,
                         float* __restrict__ posOut, int V){
    int v = blockIdx.x*blockDim.x + threadIdx.x;
    if (v >= V) return;

    float s[J][4], w[J], ps0=0.f, ps1=0.f, ps2=0.f;
    #pragma unroll
    for (int j = 0; j < J; j++){ s[j][0]=0.f; s[j][1]=0.f; s[j][2]=0.f; s[j][3]=0.f; w[j]=0.f; }

    int cnt = 0;
    for (int n = head[v]; n >= 0; n = nxt[n]){
        const float* pb = &pose[(size_t)n*J*4];
        const float* ab = &act[(size_t)n*J];
        #pragma unroll
        for (int j = 0; j < J; j++){
            float aj = ab[j];
            s[j][0] += aj*pb[j*4+0];
            s[j][1] += aj*pb[j*4+1];
            s[j][2] += aj*pb[j*4+2];
            s[j][3] += aj*pb[j*4+3];
            w[j] += aj;
        }
        ps0 += pos[(size_t)n*3+0];
        ps1 += pos[(size_t)n*3+1];
        ps2 += pos[(size_t)n*3+2];
        cnt++;
    }
    #pragma unroll
    for (int j = 0; j < J; j++){
        float inv = 1.0f/(sqrtf(s[j][0]*s[j][0]+s[j][1]*s[j][1]+
                                s[j][2]*s[j][2]+s[j][3]*s[j][3])+EPS);
        s[j][0]*=inv; s[j][1]*=inv; s[j][2]*=inv; s[j][3]*=inv;
    }
    float ag[J];
    #pragma unroll
    for (int j = 0; j < J; j++) ag[j] = 0.f;
    for (int n = head[v]; n >= 0; n = nxt[n]){
        const float* pb = &pose[(size_t)n*J*4];
        const float* ab = &act[(size_t)n*J];
        #pragma unroll
        for (int j = 0; j < J; j++){
            float agree = pb[j*4+0]*s[j][0] + pb[j*4+1]*s[j][1]
                        + pb[j*4+2]*s[j][2] + pb[j*4+3]*s[j][3];
            ag[j] += ab[j]*agree;
        }
    }
    #pragma unroll
    for (int j = 0; j < J; j++){
        size_t o = (size_t)v*J + j;
        actOut[o] = sigmoidf_(ag[j] / (w[j] + EPS));
        poseOut[o*4+0] = s[j][0];
        poseOut[o*4+1] = s[j][1];
        poseOut[o*4+2] = s[j][2];
        poseOut[o*4+3] = s[j][3];
    }
    float c = (float)cnt + EPS;
    posOut[(size_t)v*3+0] = ps0 / c;
    posOut[(size_t)v*3+1] = ps1 / c;
    posOut[(size_t)v*3+2] = ps2 / c;
}

// ---------- pools 2-3 (small V, heavy skew): node-parallel LDS-privatized ----------
template<int V, int J, int CH, int NCHUNK>
__global__ void pool_priv1(const float4* __restrict__ poseIn, const float* __restrict__ actIn,
                           const float* __restrict__ posIn,
                           float* __restrict__ s, float* __restrict__ wsum,
                           float* __restrict__ cnt, float* __restrict__ psum,
                           int N, int G, int mode, const unsigned* __restrict__ mm){
    __shared__ float s_[V*CH*4];
    __shared__ float wsum_[V*CH];
    __shared__ float cnt_[V];
    __shared__ float psum_[V*3];
    const int chunk = blockIdx.x % NCHUNK;
    const int slice = blockIdx.x / NCHUNK;
    const int nslices = gridDim.x / NCHUNK;
    const int c0 = chunk * CH;

    for (int t = threadIdx.x; t < V*CH*4; t += blockDim.x) s_[t] = 0.f;
    for (int t = threadIdx.x; t < V*CH; t += blockDim.x) wsum_[t] = 0.f;
    if (chunk == 0){
        for (int t = threadIdx.x; t < V; t += blockDim.x) cnt_[t] = 0.f;
        for (int t = threadIdx.x; t < V*3; t += blockDim.x) psum_[t] = 0.f;
    }
    __syncthreads();

    float start, size; pool_geom(mm, G, mode, start, size);
    int per = (N + nslices - 1) / nslices;
    int n0 = slice * per, n1 = min(N, n0 + per);

    for (int n = n0 + (int)threadIdx.x; n < n1; n += blockDim.x){
        int vid = voxel_id(posIn, n, G, start, size);
        #pragma unroll
        for (int jj = 0; jj < CH; jj++){
            int j = c0 + jj;
            float aj = actIn[(size_t)n*J + j];
            float4 p = poseIn[(size_t)n*J + j];
            int b = (vid*CH + jj)*4;
            atomicAdd(&s_[b+0], aj*p.x);
            atomicAdd(&s_[b+1], aj*p.y);
            atomicAdd(&s_[b+2], aj*p.z);
            atomicAdd(&s_[b+3], aj*p.w);
            atomicAdd(&wsum_[vid*CH + jj], aj);
        }
        if (chunk == 0){
            atomicAdd(&cnt_[vid], 1.0f);
            atomicAdd(&psum_[vid*3+0], posIn[(size_t)n*3+0]);
            atomicAdd(&psum_[vid*3+1], posIn[(size_t)n*3+1]);
            atomicAdd(&psum_[vid*3+2], posIn[(size_t)n*3+2]);
        }
    }
    __syncthreads();

    for (int t = threadIdx.x; t < V*CH*4; t += blockDim.x){
        float val = s_[t];
        if (val != 0.f){
            int v = t / (CH*4), r = t % (CH*4);
            atomicAdd(&s[((size_t)v*J + c0)*4 + r], val);
        }
    }
    for (int t = threadIdx.x; t < V*CH; t += blockDim.x){
        float val = wsum_[t];
        if (val != 0.f){
            int v = t / CH, jj = t % CH;
            atomicAdd(&wsum[(size_t)v*J + c0 + jj], val);
        }
    }
    if (chunk == 0){
        for (int t = threadIdx.x; t < V; t += blockDim.x)
            if (cnt_[t] != 0.f) atomicAdd(&cnt[t], cnt_[t]);
        for (int t = threadIdx.x; t < V*3; t += blockDim.x)
            if (psum_[t] != 0.f) atomicAdd(&psum[t], psum_[t]);
    }
}

template<int V, int J>
__global__ void pool_priv2(const float4* __restrict__ poseIn, const float* __restrict__ actIn,
                           const float* __restrict__ posIn, const float4* __restrict__ m,
                           float* __restrict__ agacc,
                           int N, int G, int mode, const unsigned* __restrict__ mm){
    __shared__ float ag_[V*J];
    for (int t = threadIdx.x; t < V*J; t += blockDim.x) ag_[t] = 0.f;
    __syncthreads();
    float start, size; pool_geom(mm, G, mode, start, size);
    int nslices = gridDim.x;
    int per = (N + nslices - 1) / nslices;
    int n0 = blockIdx.x * per, n1 = min(N, n0 + per);
    for (int n = n0 + (int)threadIdx.x; n < n1; n += blockDim.x){
        int vid = voxel_id(posIn, n, G, start, size);
        #pragma unroll
        for (int j = 0; j < J; j++){
            float4 p  = poseIn[(size_t)n*J + j];
            float4 mv = m[(size_t)vid*J + j];
            float agree = p.x*mv.x + p.y*mv.y + p.z*mv.z + p.w*mv.w;
            atomicAdd(&ag_[vid*J + j], actIn[(size_t)n*J + j]*agree);
        }
    }
    __syncthreads();
    for (int t = threadIdx.x; t < V*J; t += blockDim.x)
        if (ag_[t] != 0.f) atomicAdd(&agacc[t], ag_[t]);
}

__global__ void pool_m(const float* __restrict__ s, float* __restrict__ m, int VJ){
    int t = blockIdx.x*blockDim.x + threadIdx.x;
    if (t >= VJ) return;
    float a = s[(size_t)t*4], b = s[(size_t)t*4+1], c = s[(size_t)t*4+2], d = s[(size_t)t*4+3];
    float inv = 1.0f / (sqrtf(a*a + b*b + c*c + d*d) + EPS);
    m[(size_t)t*4]   = a*inv;
    m[(size_t)t*4+1] = b*inv;
    m[(size_t)t*4+2] = c*inv;
    m[(size_t)t*4+3] = d*inv;
}

__global__ void pool_fin(const float* __restrict__ agacc, const float* __restrict__ wsum,
                         const float* __restrict__ cnt, const float* __restrict__ psum,
                         float* __restrict__ actOut, float* __restrict__ posOut, int V, int J){
    int t = blockIdx.x*blockDim.x + threadIdx.x;
    if (t >= V*J) return;
    int v = t / J, j = t % J;
    actOut[t] = sigmoidf_(agacc[t] / (wsum[t] + EPS));
    if (j == 0){
        float c = cnt[v] + EPS;
        posOut[(size_t)v*3 + 0] = psum[(size_t)v*3 + 0] / c;
        posOut[(size_t)v*3 + 1] = psum[(size_t)v*3 + 1] / c;
        posOut[(size_t)v*3 + 2] = psum[(size_t)v*3 + 2] / c;
    }
}

// ---------- pool4 (N=8 -> V=1): single fused LDS kernel (trivial) ----------
template<int V, int J, int CH>
__global__ void pool_fused_kernel(const float* __restrict__ poseIn, const float* __restrict__ actIn,
                                  const float* __restrict__ posIn,
                                  float* __restrict__ poseOut, float* __restrict__ actOut,
                                  float* __restrict__ posOut,
                                  int N, int G, int mode, const unsigned* __restrict__ mm){
    __shared__ float s_[V*CH*4];
    __shared__ float wsum_[V*CH];
    __shared__ float ag_[V*CH];
    __shared__ float cnt_[V];
    __shared__ float psum_[V*3];
    const int c0 = blockIdx.x * CH;

    for (int t = threadIdx.x; t < V*CH*4; t += blockDim.x) s_[t] = 0.f;
    for (int t = threadIdx.x; t < V*CH; t += blockDim.x){ wsum_[t] = 0.f; ag_[t] = 0.f; }
    if (blockIdx.x == 0){
        for (int t = threadIdx.x; t < V; t += blockDim.x) cnt_[t] = 0.f;
        for (int t = threadIdx.x; t < V*3; t += blockDim.x) psum_[t] = 0.f;
    }
    __syncthreads();

    float start, size; pool_geom(mm, G, mode, start, size);

    for (int n = threadIdx.x; n < N; n += blockDim.x){
        int vid = voxel_id(posIn, n, G, start, size);
        #pragma unroll
        for (int jj = 0; jj < CH; jj++){
            int j = c0 + jj;
            float aj = actIn[(size_t)n*J + j];
            const float* pb = &poseIn[((size_t)n*J + j)*4];
            int b = (vid*CH + jj)*4;
            atomicAdd(&s_[b+0], aj*pb[0]);
            atomicAdd(&s_[b+1], aj*pb[1]);
            atomicAdd(&s_[b+2], aj*pb[2]);
            atomicAdd(&s_[b+3], aj*pb[3]);
            atomicAdd(&wsum_[vid*CH + jj], aj);
        }
        if (blockIdx.x == 0){
            atomicAdd(&cnt_[vid], 1.0f);
            atomicAdd(&psum_[vid*3+0], posIn[(size_t)n*3+0]);
            atomicAdd(&psum_[vid*3+1], posIn[(size_t)n*3+1]);
            atomicAdd(&psum_[vid*3+2], posIn[(size_t)n*3+2]);
        }
    }
    __syncthreads();

    for (int t = threadIdx.x; t < V*CH; t += blockDim.x){
        float a = s_[t*4], b = s_[t*4+1], c = s_[t*4+2], d = s_[t*4+3];
        float inv = 1.0f / (sqrtf(a*a + b*b + c*c + d*d) + EPS);
        s_[t*4] = a*inv; s_[t*4+1] = b*inv; s_[t*4+2] = c*inv; s_[t*4+3] = d*inv;
    }
    __syncthreads();

    for (int n = threadIdx.x; n < N; n += blockDim.x){
        int vid = voxel_id(posIn, n, G, start, size);
        #pragma unroll
        for (int jj = 0; jj < CH; jj++){
            int j = c0 + jj;
            const float* pb = &poseIn[((size_t)n*J + j)*4];
            const float* mb = &s_[(vid*CH + jj)*4];
            float agree = pb[0]*mb[0] + pb[1]*mb[1] + pb[2]*mb[2] + pb[3]*mb[3];
            atomicAdd(&ag_[vid*CH + jj], actIn[(size_t)n*J + j]*agree);
        }
    }
    __syncthreads();

    for (int t = threadIdx.x; t < V*CH; t += blockDim.x){
        int v = t / CH, jj = t % CH;
        size_t o = (size_t)v*J + c0 + jj;
        actOut[o] = sigmoidf_(ag_[t] / (wsum_[t] + EPS));
        poseOut[o*4+0] = s_[t*4+0];
        poseOut[o*4+1] = s_[t*4+1];
        poseOut[o*4+2] = s_[t*4+2];
        poseOut[o*4+3] = s_[t*4+3];
    }
    if (blockIdx.x == 0){
        for (int v = threadIdx.x; v < V; v += blockDim.x){
            float c = cnt_[v] + EPS;
            posOut[(size_t)v*3+0] = psum_[(size_t)v*3+0] / c;
            posOut[(size_t)v*3+1] = psum_[(size_t)v*3+1] / c;
            posOut[(size_t)v*3+2] = psum_[(size_t)v*3+2] / c;
        }
    }
}

extern "C" void kernel_launch(void* const* d_in, const int* in_sizes, int n_in,
                              void* d_out, int out_size, void* d_ws, size_t ws_size,
                              hipStream_t stream){
    const float* x      = (const float*)d_in[0];
    const float* pos    = (const float*)d_in[1];
    const float* pseudo = (const float*)d_in[2];
    const float* Wsp    = (const float*)d_in[3];
    const float* root   = (const float*)d_in[4];
    const float* bias   = (const float*)d_in[5];
    const float* lin_w  = (const float*)d_in[6];
    const float* lin_b  = (const float*)d_in[7];
    const float* q0     = (const float*)d_in[8];
    const float* q1     = (const float*)d_in[9];
    const float* q3     = (const float*)d_in[10];
    const float* q5     = (const float*)d_in[11];
    const float* q6     = (const float*)d_in[12];
    const float* q7     = (const float*)d_in[13];
    const int*   ei     = (const int*)d_in[14];
    const int N = in_sizes[0];
    const int E = in_sizes[2] / 3;
    const int V1 = 32768;

    char* ws = (char*)d_ws;
    size_t off = 0;
    auto alloc = [&](size_t bytes)->void*{
        void* p = ws + off;
        off += (bytes + 255) & ~(size_t)255;
        return p;
    };
    unsigned* mm   = (unsigned*)alloc(8);
    int* ehead     = (int*)alloc((size_t)4*N*sizeof(int));
    int* enxt      = (int*)alloc((size_t)E*sizeof(int));
    int* vhead     = (int*)alloc((size_t)V1*sizeof(int));
    int* vnxt      = (int*)alloc((size_t)N*sizeof(int));
    float* P0  = (float*)alloc((size_t)1250000*sizeof(float));
    float* P1  = (float*)alloc((size_t)1250000*sizeof(float));
    float* A0  = (float*)alloc((size_t)310000*sizeof(float));
    float* A1  = (float*)alloc((size_t)310000*sizeof(float));
    float* PB0 = (float*)alloc((size_t)100000*sizeof(float));
    float* PB1 = (float*)alloc((size_t)100000*sizeof(float));
    size_t pool_off0 = off;                     // shared pool scratch region
    float* vs  = (float*)alloc((size_t)512*8*4*sizeof(float));
    float* vw  = (float*)alloc((size_t)512*8*sizeof(float));
    float* va  = (float*)alloc((size_t)512*8*sizeof(float));
    float* vc  = (float*)alloc((size_t)512*sizeof(float));
    float* vp  = (float*)alloc((size_t)512*3*sizeof(float));
    size_t pool_bytes = off - pool_off0;

    hipMemsetAsync(mm,     0xFF, 4, stream);
    hipMemsetAsync(mm + 1, 0x00, 4, stream);
    hipMemsetAsync(ehead, 0xFF, (size_t)4*N*sizeof(int), stream); // -1
    hipMemsetAsync(vhead, 0xFF, (size_t)V1*sizeof(int), stream);  // -1

    minmax_kernel<<<80, 256, 0, stream>>>(pos, N*3, mm);

    // 4-way split linked lists; walker = thread per (node, sub-chain)
    elist_edge<<<(E + 255)/256, 256, 0, stream>>>(ei, ehead, enxt, E, N);
    spline_node_kernel<<<(4*N + 255)/256, 256, 0, stream>>>(x, pseudo, ei, ehead, enxt, Wsp,
                                                            root, bias, lin_w, lin_b, P0, A0, N, E);

    // capsule layers: all cooperative (spill-free)
    caps_coop_kernel<1,6,32><<<(N + 31)/32, 32*6, 0, stream>>>(P0, A0, q0, P1, A1, N);
    caps_coop_kernel<6,6,7><<<(N + 6)/7, 7*36, 0, stream>>>(P1, A1, q1, P0, A0, N);

    // pool1: 50000 -> 32768 voxels (G=32), J=6 — linked-list thread-per-voxel gather
    {
        const int G = 32;
        elist_node<<<(N + 255)/256, 256, 0, stream>>>(pos, vhead, vnxt, N, G, 0, mm);
        pool1_gather_kernel<6><<<(V1 + 255)/256, 256, 0, stream>>>(P0, A0, pos, vhead, vnxt,
                                                                   P1, A1, PB0, V1);
    }
    caps_coop_kernel<6,8,5><<<(32768 + 4)/5, 5*48, 0, stream>>>(P1, A1, q3, P0, A0, 32768);

    // pool2: 32768 -> 512 (G=8), J=8 — node-parallel LDS-privatized, 64 slices
    {
        const int V = 512, J = 8, G = 8, NSL = 64;
        hipMemsetAsync(vs, 0, pool_bytes, stream);
        pool_priv1<V,J,4,2><<<2*NSL, 256, 0, stream>>>((const float4*)P0, A0, PB0,
                                                       vs, vw, vc, vp, 32768, G, 0, mm);
        pool_m<<<(V*J + 255)/256, 256, 0, stream>>>(vs, P1, V*J);
        pool_priv2<V,J><<<NSL, 256, 0, stream>>>((const float4*)P0, A0, PB0,
                                                 (const float4*)P1, va, 32768, G, 0, mm);
        pool_fin<<<(V*J + 255)/256, 256, 0, stream>>>(va, vw, vc, vp, A1, PB1, V, J);
    }
    caps_coop_kernel<8,12,2><<<256, 2*96, 0, stream>>>(P1, A1, q5, P0, A0, 512);

    // pool3: 512 -> 8 (G=2), J=12 — node-parallel privatized, 16 slices
    {
        const int V = 8, J = 12, G = 2, NSL = 16;
        hipMemsetAsync(vs, 0, pool_bytes, stream);
        pool_priv1<V,J,12,1><<<NSL, 256, 0, stream>>>((const float4*)P0, A0, PB1,
                                                      vs, vw, vc, vp, 512, G, 0, mm);
        pool_m<<<1, 256, 0, stream>>>(vs, P1, V*J);
        pool_priv2<V,J><<<NSL, 256, 0, stream>>>((const float4*)P0, A0, PB1,
                                                 (const float4*)P1, va, 512, G, 0, mm);
        pool_fin<<<1, 256, 0, stream>>>(va, vw, vc, vp, A1, PB0, V, J);
    }
    caps_coop_kernel<12,14,1><<<8, 168, 0, stream>>>(P1, A1, q6, P0, A0, 8);

    // pool4: 8 -> 1 (G=1, mode=1), J=14 — fused LDS path, 1 block (trivial N)
    pool_fused_kernel<1,14,14><<<1, 1024, 0, stream>>>(P0, A0, PB0, P1, A1, PB1, 8, 1, 1, mm);
    caps_coop_kernel<14,10,1><<<1, 140, 0, stream>>>(P1, A1, q7, P0, (float*)d_out, 1);
}